// Round 8
// baseline (318.710 us; speedup 1.0000x reference)
//
#include <hip/hip_runtime.h>

// Three-kernel structure (all in one graph-captured stream):
//  1) bbox_init: d_ws[0..31] = 0xFFFFFFFF (8 batches x 4 unsigned mins).
//  2) scan_copy: flat float4 copy img->out for ALL pixels + for sel batches,
//     per-batch bbox of re_mask!=1 entries via wave-reduced unsigned atomicMin.
//     Encodings: [0]=min y, [1]=min(511-y), [2]=min x, [3]=min(511-x)  -> maxes
//     recovered as 511-enc. Outside bbox mask==1 -> out=img (general, any mask).
//  3) gdfn_heavy2: each block recomputes the compact enumeration of tiles
//     overlapping any sel batch's bbox (from 8 bboxes, in registers -> no queue),
//     grid-strides over exactly those ~2704 tiles, runs the R7 heavy pipeline
//     (bit-identical math). No per-tile mask scan, no fast-exit dispatch waste.
// img_p (padded img+noise) radius 3 -> 14x14/ch; img_r radius 2 -> 12x12;
// img_3d_mod radius 1 -> 10x10.
#define TS 8
#define PW 14
#define PS 15   // LDS row stride (pad +1)
#define RW 12
#define RS 13
#define MW 10
#define MS 11

#define NSCAN 2048     // scan_copy blocks (x256 thr, 3 float4 iters each: exact)
#define NHVY  4096     // heavy-role blocks

__global__ __launch_bounds__(64)
void bbox_init(unsigned* __restrict__ ws)
{
    if (threadIdx.x < 32) ws[threadIdx.x] = 0xFFFFFFFFu;
}

__global__ __launch_bounds__(256)
void scan_copy(const float4* __restrict__ img4,
               const float4* __restrict__ mask4,
               float4*       __restrict__ out4,
               const int*    __restrict__ sel,
               unsigned*     __restrict__ bbox)
{
    // 8 batches x 196608 float4 = 1572864 total = NSCAN*256*3 exactly.
    const int base = blockIdx.x * 256 + threadIdx.x;
#pragma unroll
    for (int it = 0; it < 3; ++it) {
        const int i = base + it * (NSCAN * 256);
        out4[i] = img4[i];                       // copy role (heavy tiles rewritten later)
        const unsigned b = (unsigned)i / 196608u;   // wave-uniform (196608 % 64 == 0)
        if (sel[b]) {
            const float4 m = mask4[i];
            const bool n0 = (m.x != 1.f), n1 = (m.y != 1.f),
                       n2 = (m.z != 1.f), n3 = (m.w != 1.f);
            unsigned ymin = 0xFFFFFFFFu, ymaxe = 0xFFFFFFFFu,
                     xmin = 0xFFFFFFFFu, xmaxe = 0xFFFFFFFFu;
            if (n0 | n1 | n2 | n3) {
                const unsigned r   = (unsigned)i - b * 196608u;
                const unsigned rem = r & 65535u;        // within channel (HW/4 = 65536)
                const unsigned pix = rem << 2;
                const unsigned y   = pix >> 9;          // W = 512
                const unsigned x   = pix & 511u;
                const unsigned f = n0 ? 0u : (n1 ? 1u : (n2 ? 2u : 3u));
                const unsigned l = n3 ? 3u : (n2 ? 2u : (n1 ? 1u : 0u));
                ymin  = y;            ymaxe = 511u - y;
                xmin  = x + f;        xmaxe = 511u - (x + l);
            }
            // full-wave min reduction (branch is wave-uniform -> all 64 lanes here)
#pragma unroll
            for (int off = 32; off; off >>= 1) {
                ymin  = min(ymin,  (unsigned)__shfl_xor((int)ymin,  off));
                ymaxe = min(ymaxe, (unsigned)__shfl_xor((int)ymaxe, off));
                xmin  = min(xmin,  (unsigned)__shfl_xor((int)xmin,  off));
                xmaxe = min(xmaxe, (unsigned)__shfl_xor((int)xmaxe, off));
            }
            if ((threadIdx.x & 63) == 0 && ymin != 0xFFFFFFFFu) {
                atomicMin(&bbox[b * 4 + 0], ymin);
                atomicMin(&bbox[b * 4 + 1], ymaxe);
                atomicMin(&bbox[b * 4 + 2], xmin);
                atomicMin(&bbox[b * 4 + 3], xmaxe);
            }
        }
    }
}

__global__ __launch_bounds__(256, 8)
void gdfn_heavy2(const float* __restrict__ img,
                 const float* __restrict__ noise,
                 const float* __restrict__ re_mask,
                 const int*   __restrict__ sel,
                 const int*   __restrict__ mix_sel,
                 float*       __restrict__ out,
                 const unsigned* __restrict__ bbox)
{
    constexpr int H = 512, W = 512, HP = 514, WP = 514;
    const int tid = threadIdx.x;

    // Per-batch tile rects + compact counts (uniform scalar work, all threads).
    int ty0a[8], tx0a[8], twa[8], cnta[8];
    int total = 0;
#pragma unroll
    for (int b = 0; b < 8; ++b) {
        int c = 0; ty0a[b] = 0; tx0a[b] = 0; twa[b] = 1;
        if (sel[b]) {
            const unsigned ymin = bbox[b * 4 + 0];
            if (ymin <= 511u) {
                const int ty0 = (int)(ymin >> 3);
                const int ty1 = (int)((511u - bbox[b * 4 + 1]) >> 3);
                const int tx0 = (int)(bbox[b * 4 + 2] >> 3);
                const int tx1 = (int)((511u - bbox[b * 4 + 3]) >> 3);
                const int tw = tx1 - tx0 + 1;
                c = (ty1 - ty0 + 1) * tw;
                ty0a[b] = ty0; tx0a[b] = tx0; twa[b] = tw;
            }
        }
        cnta[b] = c;
        total += c;
    }

    __shared__ float s_imgp[3 * PW * PS];   // 2520 B
    __shared__ float s_w   [RW * RW * 9];   // w3 per stage-1 pixel, 5184 B
    __shared__ float s_imgr[RW * RS];       //  624 B
    __shared__ float s_mod [MW * MS];       //  440 B

    const size_t HWs = (size_t)H * W;

    for (int hid = blockIdx.x; hid < total; hid += NHVY) {
        __syncthreads();                    // LDS reuse across grid-stride iters

        // Decode hid -> (batch, tile h0/w0) from the compact enumeration.
        int b = 0, rem = hid;
#pragma unroll
        for (int q = 0; q < 8; ++q) {
            if (rem >= cnta[q] && b == q) { rem -= cnta[q]; b = q + 1; }
        }
        const int tw = twa[b];
        const int h0 = (ty0a[b] + rem / tw) * TS;
        const int w0 = (tx0a[b] + rem % tw) * TS;

        const size_t imgB = (size_t)b * 3 * HWs;
        const size_t noiB = (size_t)b * 3 * HP * WP;
        const int msel = mix_sel[b];

        // stage-3 per-(pixel,channel) loads issued early (threads 0..191)
        const int c3  = tid >> 6;
        const int p3i = tid & 63;
        const int t3y = p3i >> 3, t3x = p3i & 7;
        const int g3y = h0 + t3y, g3x = w0 + t3x;
        const size_t o3 = imgB + (size_t)c3 * HWs + (size_t)g3y * W + g3x;
        float img3v = 0.f, rm3v = 0.f;
        if (tid < 192) {
            img3v = img[o3];
            rm3v  = re_mask[o3];
        }

        // Stage 0: img_p = pad(img,1)+noise over padded [h0-2, h0+11]^2, 588 elems.
#pragma unroll
        for (int it = 0; it < 3; ++it) {
            int idx = tid + it * 256;
            if (idx < 3 * PW * PW) {
                int c  = idx / (PW * PW);
                int r  = idx - c * (PW * PW);
                int ly = r / PW, lx = r - ly * PW;
                int py = h0 - 2 + ly, px = w0 - 2 + lx;   // padded coords
                float v = 0.f;
                if (py >= 0 && py < HP && px >= 0 && px < WP) {
                    v = noise[noiB + (size_t)c * HP * WP + (size_t)py * WP + px];
                    int iy = py - 1, ix = px - 1;
                    if (iy >= 0 && iy < H && ix >= 0 && ix < W)
                        v += img[imgB + (size_t)c * HWs + (size_t)iy * W + ix];
                }
                s_imgp[c * PW * PS + ly * PS + lx] = v;
            }
        }
        __syncthreads();

        // Stage 1: per pixel (12x12 = 144), all 3 channels in registers.
        // w = exp(-(x-mean)^2/(2*std^2)), std^2(ddof=1)=ssd/8 => exp(-4 d^2/ssd)
        if (tid < RW * RW) {
            int sy = tid / RW, sx = tid - sy * RW;
            int ry = h0 - 2 + sy, rx = w0 - 2 + sx;
            if (ry >= 0 && ry < H && rx >= 0 && rx < W) {
                float w3[9], vs[9];
#pragma unroll
                for (int c = 0; c < 3; ++c) {
                    const float* sp = &s_imgp[c * PW * PS + sy * PS + sx];
                    float v[9];
                    float sum = 0.f;
#pragma unroll
                    for (int i = 0; i < 3; ++i)
#pragma unroll
                        for (int j = 0; j < 3; ++j) {
                            float x = sp[i * PS + j];
                            v[i * 3 + j] = x;
                            sum += x;
                        }
                    float mean = sum * (1.f / 9.f);
                    float ssd = 0.f;
#pragma unroll
                    for (int k = 0; k < 9; ++k) { float d = v[k] - mean; ssd += d * d; }
                    float inv = -4.f / ssd;
#pragma unroll
                    for (int k = 0; k < 9; ++k) {
                        float d  = v[k] - mean;
                        float wv = __expf(d * d * inv);
                        if (c == 0) { w3[k] = wv;               vs[k] = v[k];  }
                        else        { w3[k] = fminf(w3[k], wv); vs[k] += v[k]; }
                    }
                }
                float num = 0.f, den = 0.f;
#pragma unroll
                for (int k = 0; k < 9; ++k) {
                    den += w3[k];
                    num += vs[k] * w3[k];
                }
                s_imgr[sy * RS + sx] = num / den;
                float* wd = &s_w[tid * 9];
#pragma unroll
                for (int k = 0; k < 9; ++k) wd[k] = w3[k];
            }
        }
        __syncthreads();

        // Stage 2: per pixel (10x10): first-occurrence argmin/argmax over img_r
        // 3x3 (OOB = 0.0 exactly); selected weight read from cached w3.
        if (tid < MW * MW) {
            int my = tid / MW, mx = tid - my * MW;
            int qy = h0 - 1 + my, qx = w0 - 1 + mx;
            if (qy >= 0 && qy < H && qx >= 0 && qx < W) {
                float bmin = 0.f, bmax = 0.f;
                int imin = 0, imax = 0;
#pragma unroll
                for (int k = 0; k < 9; ++k) {
                    int di = k / 3 - 1, dj = k % 3 - 1;
                    int ny = qy + di, nx = qx + dj;
                    float val = 0.f;
                    if (ny >= 0 && ny < H && nx >= 0 && nx < W)
                        val = s_imgr[(my + 1 + di) * RS + (mx + 1 + dj)];
                    if (k == 0) { bmin = val; bmax = val; }
                    else {
                        if (val < bmin) { bmin = val; imin = k; }
                        if (val > bmax) { bmax = val; imax = k; }
                    }
                }
                int ks = msel ? imax : imin;
                int rp = (my + 1) * RW + (mx + 1);
                s_mod[my * MS + mx] = s_w[rp * 9 + ks];
            }
        }
        __syncthreads();

        // Stage 3: per (pixel, channel), 192 threads.
        if (tid < 192) {
            float m[9];
            float mden = 0.f;
#pragma unroll
            for (int k = 0; k < 9; ++k) {
                int di = k / 3 - 1, dj = k % 3 - 1;
                int ny = g3y + di, nx = g3x + dj;
                float mv = 0.f;
                if (ny >= 0 && ny < H && nx >= 0 && nx < W)
                    mv = s_mod[(t3y + di + 1) * MS + (t3x + dj + 1)];
                m[k] = mv;
                mden += mv;
            }
            const float* sp = &s_imgp[c3 * PW * PS + (t3y + 2) * PS + (t3x + 2)];
            float numc = 0.f;
#pragma unroll
            for (int i = 0; i < 3; ++i)
#pragma unroll
                for (int j = 0; j < 3; ++j)
                    numc += sp[i * PS + j] * m[i * 3 + j];
            float imod = numc / mden;
            out[o3] = imod * (1.f - rm3v) + img3v * rm3v;
        }
    }
}

extern "C" void kernel_launch(void* const* d_in, const int* in_sizes, int n_in,
                              void* d_out, int out_size, void* d_ws, size_t ws_size,
                              hipStream_t stream)
{
    const float* img     = (const float*)d_in[0];
    const float* noise   = (const float*)d_in[1];
    const float* re_mask = (const float*)d_in[2];
    const int*   sel     = (const int*)d_in[3];
    const int*   mix_sel = (const int*)d_in[4];
    float*       out     = (float*)d_out;
    unsigned*    bbox    = (unsigned*)d_ws;

    hipLaunchKernelGGL(bbox_init, dim3(1), dim3(64), 0, stream, bbox);
    hipLaunchKernelGGL(scan_copy, dim3(NSCAN), dim3(256), 0, stream,
                       (const float4*)img, (const float4*)re_mask, (float4*)out,
                       sel, bbox);
    hipLaunchKernelGGL(gdfn_heavy2, dim3(NHVY), dim3(256), 0, stream,
                       img, noise, re_mask, sel, mix_sel, out, bbox);
}

// Round 9
// 162.909 us; speedup vs baseline: 1.9564x; 1.9564x over previous
//
#include <hip/hip_runtime.h>

// Four tiny kernels in one stream (graph-captured):
//  1) bbox_init: clear 64 slots x 32 words + 32-word final to 0xFFFFFFFF.
//  2) scan_copy: flat float4 copy img->out for ALL pixels + for sel batches,
//     per-batch bbox of re_mask!=1 via wave-reduced unsigned atomicMin into
//     slot (blockIdx & 63) -- each slot its own 128B line. R8 put all atomics
//     on ONE line -> ~19k same-line atomics serialized at L2 (~177us, VALU 0.9%).
//  3) bbox_reduce: 1 block folds 64 slots -> final bbox[32] (independent loads).
//  4) gdfn_heavy2: compact enumeration of bbox-overlapping tiles from final
//     bbox (registers, no queue); grid-stride; R7 heavy pipeline verbatim.
// Encodings: [0]=min y, [1]=min(511-y), [2]=min x, [3]=min(511-x).
// img_p radius 3 -> 14x14/ch; img_r radius 2 -> 12x12; mod radius 1 -> 10x10.
#define TS 8
#define PW 14
#define PS 15
#define RW 12
#define RS 13
#define MW 10
#define MS 11

#define NSCAN 2048     // scan_copy blocks (x256 thr, 3 float4 iters each: exact)
#define NHVY  4096     // heavy-role blocks
#define NSLOT 64       // bbox atomic slots (one 128B line each)

__global__ __launch_bounds__(256)
void bbox_init(unsigned* __restrict__ ws)
{
    // clear slots[64*32] + final[32] = 2080 words
    for (int i = threadIdx.x; i < NSLOT * 32 + 32; i += 256)
        ws[i] = 0xFFFFFFFFu;
}

__global__ __launch_bounds__(256)
void scan_copy(const float4* __restrict__ img4,
               const float4* __restrict__ mask4,
               float4*       __restrict__ out4,
               const int*    __restrict__ sel,
               unsigned*     __restrict__ slots)
{
    // 8 batches x 196608 float4 = 1572864 total = NSCAN*256*3 exactly.
    const int base = blockIdx.x * 256 + threadIdx.x;
    unsigned* slot = slots + (blockIdx.x & (NSLOT - 1)) * 32;
#pragma unroll
    for (int it = 0; it < 3; ++it) {
        const int i = base + it * (NSCAN * 256);
        out4[i] = img4[i];                       // copy role (heavy tiles rewritten later)
        const unsigned b = (unsigned)i / 196608u;   // wave-uniform (196608 % 64 == 0)
        if (sel[b]) {
            const float4 m = mask4[i];
            const bool n0 = (m.x != 1.f), n1 = (m.y != 1.f),
                       n2 = (m.z != 1.f), n3 = (m.w != 1.f);
            unsigned ymin = 0xFFFFFFFFu, ymaxe = 0xFFFFFFFFu,
                     xmin = 0xFFFFFFFFu, xmaxe = 0xFFFFFFFFu;
            if (n0 | n1 | n2 | n3) {
                const unsigned r   = (unsigned)i - b * 196608u;
                const unsigned rem = r & 65535u;        // within channel (HW/4)
                const unsigned pix = rem << 2;
                const unsigned y   = pix >> 9;          // W = 512
                const unsigned x   = pix & 511u;
                const unsigned f = n0 ? 0u : (n1 ? 1u : (n2 ? 2u : 3u));
                const unsigned l = n3 ? 3u : (n2 ? 2u : (n1 ? 1u : 0u));
                ymin  = y;            ymaxe = 511u - y;
                xmin  = x + f;        xmaxe = 511u - (x + l);
            }
            // full-wave min reduction (wave-uniform branch -> all 64 lanes here)
#pragma unroll
            for (int off = 32; off; off >>= 1) {
                ymin  = min(ymin,  (unsigned)__shfl_xor((int)ymin,  off));
                ymaxe = min(ymaxe, (unsigned)__shfl_xor((int)ymaxe, off));
                xmin  = min(xmin,  (unsigned)__shfl_xor((int)xmin,  off));
                xmaxe = min(xmaxe, (unsigned)__shfl_xor((int)xmaxe, off));
            }
            if ((threadIdx.x & 63) == 0 && ymin != 0xFFFFFFFFu) {
                atomicMin(&slot[b * 4 + 0], ymin);
                atomicMin(&slot[b * 4 + 1], ymaxe);
                atomicMin(&slot[b * 4 + 2], xmin);
                atomicMin(&slot[b * 4 + 3], xmaxe);
            }
        }
    }
}

__global__ __launch_bounds__(64)
void bbox_reduce(const unsigned* __restrict__ slots, unsigned* __restrict__ final32)
{
    const int w = threadIdx.x;
    if (w < 32) {
        unsigned m = 0xFFFFFFFFu;
#pragma unroll
        for (int s = 0; s < NSLOT; ++s)          // independent loads, pipelined
            m = min(m, slots[s * 32 + w]);
        final32[w] = m;
    }
}

__global__ __launch_bounds__(256, 8)
void gdfn_heavy2(const float* __restrict__ img,
                 const float* __restrict__ noise,
                 const float* __restrict__ re_mask,
                 const int*   __restrict__ sel,
                 const int*   __restrict__ mix_sel,
                 float*       __restrict__ out,
                 const unsigned* __restrict__ bbox)
{
    constexpr int H = 512, W = 512, HP = 514, WP = 514;
    const int tid = threadIdx.x;

    // Per-batch tile rects + compact counts (uniform scalar work, all threads).
    int ty0a[8], tx0a[8], twa[8], cnta[8];
    int total = 0;
#pragma unroll
    for (int b = 0; b < 8; ++b) {
        int c = 0; ty0a[b] = 0; tx0a[b] = 0; twa[b] = 1;
        if (sel[b]) {
            const unsigned ymin = bbox[b * 4 + 0];
            if (ymin <= 511u) {
                const int ty0 = (int)(ymin >> 3);
                const int ty1 = (int)((511u - bbox[b * 4 + 1]) >> 3);
                const int tx0 = (int)(bbox[b * 4 + 2] >> 3);
                const int tx1 = (int)((511u - bbox[b * 4 + 3]) >> 3);
                const int tw = tx1 - tx0 + 1;
                c = (ty1 - ty0 + 1) * tw;
                ty0a[b] = ty0; tx0a[b] = tx0; twa[b] = tw;
            }
        }
        cnta[b] = c;
        total += c;
    }

    __shared__ float s_imgp[3 * PW * PS];   // 2520 B
    __shared__ float s_w   [RW * RW * 9];   // w3 per stage-1 pixel, 5184 B
    __shared__ float s_imgr[RW * RS];       //  624 B
    __shared__ float s_mod [MW * MS];       //  440 B

    const size_t HWs = (size_t)H * W;

    for (int hid = blockIdx.x; hid < total; hid += NHVY) {
        __syncthreads();                    // LDS reuse across grid-stride iters

        // Decode hid -> (batch, tile h0/w0) from the compact enumeration.
        int b = 0, rem = hid;
#pragma unroll
        for (int q = 0; q < 8; ++q) {
            if (rem >= cnta[q] && b == q) { rem -= cnta[q]; b = q + 1; }
        }
        const int tw = twa[b];
        const int h0 = (ty0a[b] + rem / tw) * TS;
        const int w0 = (tx0a[b] + rem % tw) * TS;

        const size_t imgB = (size_t)b * 3 * HWs;
        const size_t noiB = (size_t)b * 3 * HP * WP;
        const int msel = mix_sel[b];

        // stage-3 per-(pixel,channel) loads issued early (threads 0..191)
        const int c3  = tid >> 6;
        const int p3i = tid & 63;
        const int t3y = p3i >> 3, t3x = p3i & 7;
        const int g3y = h0 + t3y, g3x = w0 + t3x;
        const size_t o3 = imgB + (size_t)c3 * HWs + (size_t)g3y * W + g3x;
        float img3v = 0.f, rm3v = 0.f;
        if (tid < 192) {
            img3v = img[o3];
            rm3v  = re_mask[o3];
        }

        // Stage 0: img_p = pad(img,1)+noise over padded [h0-2, h0+11]^2, 588 elems.
#pragma unroll
        for (int it = 0; it < 3; ++it) {
            int idx = tid + it * 256;
            if (idx < 3 * PW * PW) {
                int c  = idx / (PW * PW);
                int r  = idx - c * (PW * PW);
                int ly = r / PW, lx = r - ly * PW;
                int py = h0 - 2 + ly, px = w0 - 2 + lx;   // padded coords
                float v = 0.f;
                if (py >= 0 && py < HP && px >= 0 && px < WP) {
                    v = noise[noiB + (size_t)c * HP * WP + (size_t)py * WP + px];
                    int iy = py - 1, ix = px - 1;
                    if (iy >= 0 && iy < H && ix >= 0 && ix < W)
                        v += img[imgB + (size_t)c * HWs + (size_t)iy * W + ix];
                }
                s_imgp[c * PW * PS + ly * PS + lx] = v;
            }
        }
        __syncthreads();

        // Stage 1: per pixel (12x12 = 144), all 3 channels in registers.
        // w = exp(-(x-mean)^2/(2*std^2)), std^2(ddof=1)=ssd/8 => exp(-4 d^2/ssd)
        if (tid < RW * RW) {
            int sy = tid / RW, sx = tid - sy * RW;
            int ry = h0 - 2 + sy, rx = w0 - 2 + sx;
            if (ry >= 0 && ry < H && rx >= 0 && rx < W) {
                float w3[9], vs[9];
#pragma unroll
                for (int c = 0; c < 3; ++c) {
                    const float* sp = &s_imgp[c * PW * PS + sy * PS + sx];
                    float v[9];
                    float sum = 0.f;
#pragma unroll
                    for (int i = 0; i < 3; ++i)
#pragma unroll
                        for (int j = 0; j < 3; ++j) {
                            float x = sp[i * PS + j];
                            v[i * 3 + j] = x;
                            sum += x;
                        }
                    float mean = sum * (1.f / 9.f);
                    float ssd = 0.f;
#pragma unroll
                    for (int k = 0; k < 9; ++k) { float d = v[k] - mean; ssd += d * d; }
                    float inv = -4.f / ssd;
#pragma unroll
                    for (int k = 0; k < 9; ++k) {
                        float d  = v[k] - mean;
                        float wv = __expf(d * d * inv);
                        if (c == 0) { w3[k] = wv;               vs[k] = v[k];  }
                        else        { w3[k] = fminf(w3[k], wv); vs[k] += v[k]; }
                    }
                }
                float num = 0.f, den = 0.f;
#pragma unroll
                for (int k = 0; k < 9; ++k) {
                    den += w3[k];
                    num += vs[k] * w3[k];
                }
                s_imgr[sy * RS + sx] = num / den;
                float* wd = &s_w[tid * 9];
#pragma unroll
                for (int k = 0; k < 9; ++k) wd[k] = w3[k];
            }
        }
        __syncthreads();

        // Stage 2: per pixel (10x10): first-occurrence argmin/argmax over img_r
        // 3x3 (OOB = 0.0 exactly); selected weight read from cached w3.
        if (tid < MW * MW) {
            int my = tid / MW, mx = tid - my * MW;
            int qy = h0 - 1 + my, qx = w0 - 1 + mx;
            if (qy >= 0 && qy < H && qx >= 0 && qx < W) {
                float bmin = 0.f, bmax = 0.f;
                int imin = 0, imax = 0;
#pragma unroll
                for (int k = 0; k < 9; ++k) {
                    int di = k / 3 - 1, dj = k % 3 - 1;
                    int ny = qy + di, nx = qx + dj;
                    float val = 0.f;
                    if (ny >= 0 && ny < H && nx >= 0 && nx < W)
                        val = s_imgr[(my + 1 + di) * RS + (mx + 1 + dj)];
                    if (k == 0) { bmin = val; bmax = val; }
                    else {
                        if (val < bmin) { bmin = val; imin = k; }
                        if (val > bmax) { bmax = val; imax = k; }
                    }
                }
                int ks = msel ? imax : imin;
                int rp = (my + 1) * RW + (mx + 1);
                s_mod[my * MS + mx] = s_w[rp * 9 + ks];
            }
        }
        __syncthreads();

        // Stage 3: per (pixel, channel), 192 threads.
        if (tid < 192) {
            float m[9];
            float mden = 0.f;
#pragma unroll
            for (int k = 0; k < 9; ++k) {
                int di = k / 3 - 1, dj = k % 3 - 1;
                int ny = g3y + di, nx = g3x + dj;
                float mv = 0.f;
                if (ny >= 0 && ny < H && nx >= 0 && nx < W)
                    mv = s_mod[(t3y + di + 1) * MS + (t3x + dj + 1)];
                m[k] = mv;
                mden += mv;
            }
            const float* sp = &s_imgp[c3 * PW * PS + (t3y + 2) * PS + (t3x + 2)];
            float numc = 0.f;
#pragma unroll
            for (int i = 0; i < 3; ++i)
#pragma unroll
                for (int j = 0; j < 3; ++j)
                    numc += sp[i * PS + j] * m[i * 3 + j];
            float imod = numc / mden;
            out[o3] = imod * (1.f - rm3v) + img3v * rm3v;
        }
    }
}

extern "C" void kernel_launch(void* const* d_in, const int* in_sizes, int n_in,
                              void* d_out, int out_size, void* d_ws, size_t ws_size,
                              hipStream_t stream)
{
    const float* img     = (const float*)d_in[0];
    const float* noise   = (const float*)d_in[1];
    const float* re_mask = (const float*)d_in[2];
    const int*   sel     = (const int*)d_in[3];
    const int*   mix_sel = (const int*)d_in[4];
    float*       out     = (float*)d_out;
    unsigned*    slots   = (unsigned*)d_ws;            // [64][32]
    unsigned*    final32 = slots + NSLOT * 32;         // [32]

    hipLaunchKernelGGL(bbox_init, dim3(1), dim3(256), 0, stream, slots);
    hipLaunchKernelGGL(scan_copy, dim3(NSCAN), dim3(256), 0, stream,
                       (const float4*)img, (const float4*)re_mask, (float4*)out,
                       sel, slots);
    hipLaunchKernelGGL(bbox_reduce, dim3(1), dim3(64), 0, stream, slots, final32);
    hipLaunchKernelGGL(gdfn_heavy2, dim3(NHVY), dim3(256), 0, stream,
                       img, noise, re_mask, sel, mix_sel, out, final32);
}

// Round 10
// 149.541 us; speedup vs baseline: 2.1313x; 1.0894x over previous
//
#include <hip/hip_runtime.h>

// Two dispatches:
//  1) mask_scan: per-batch bbox of re_mask!=1 (sel batches only; each block owns
//     1536 consecutive float4s of ONE batch). Per-lane running mins -> wave
//     shuffle reduce -> cross-wave LDS reduce -> <=4 atomicMin per block into
//     slot (blockIdx&63) [own 128B line each; R8's single-line atomics = 177us].
//     No init kernel: d_ws poison 0xAA... = huge unsigned (atomicMin-safe);
//     stale values are same-input mins (idempotent); bbox over-coverage is
//     harmless because copy-skip and heavy enumeration use the SAME words.
//  2) gdfn_all: heavy-role blocks (bid<NHVY) first: grid-stride over compact
//     enumeration of 32x8 tiles covering the bbox (row-shaped => every global
//     access is a >=128B contiguous segment; R9's 8x8 tiles fetched 56B scraps
//     at 1TB/s). Copy-role blocks stream img->out, skipping the tile-aligned
//     rect (disjoint writers). w3 LDS cache dropped (stage 2 recomputes, R4
//     formula, bit-identical) -> LDS 9.7KB, 8 blocks/CU.
// Encodings: [0]=min y, [1]=min(511-y), [2]=min x, [3]=min(511-x).
#define TSY 8
#define TSX 32
#define PH  14     // TSY+6 rows of img_p
#define PWX 38     // TSX+6 cols
#define PXS 39     // LDS stride
#define RH  12     // img_r domain rows (radius 2)
#define RWX 36
#define RXS 37
#define MH  10     // mod domain rows (radius 1)
#define MWX 34
#define MXS 35

#define NSLOT 64
#define NMSK  1024     // mask_scan blocks: 128 per batch, 1536 float4 each
#define NHVY  1024     // heavy-role blocks
#define NCPY  2048     // copy-role blocks (x256 thr x3 iters = exact cover)

__global__ __launch_bounds__(256)
void mask_scan(const float4* __restrict__ mask4,
               const int*    __restrict__ sel,
               unsigned*     __restrict__ slots)
{
    const int b = blockIdx.x >> 7;            // 128 blocks per batch (block-uniform)
    if (!sel[b]) return;
    const int base = blockIdx.x * (256 * 6) + threadIdx.x;
    unsigned ymin = ~0u, ymaxe = ~0u, xmin = ~0u, xmaxe = ~0u;
#pragma unroll
    for (int it = 0; it < 6; ++it) {
        const int i = base + it * 256;        // 1536 consecutive f4 per block
        const float4 m = mask4[i];
        const bool n0 = m.x != 1.f, n1 = m.y != 1.f, n2 = m.z != 1.f, n3 = m.w != 1.f;
        if (n0 | n1 | n2 | n3) {
            const unsigned pix = ((unsigned)i & 65535u) << 2;  // strides % 65536 == 0
            const unsigned y = pix >> 9, x = pix & 511u;
            const unsigned f = n0 ? 0u : (n1 ? 1u : (n2 ? 2u : 3u));
            const unsigned l = n3 ? 3u : (n2 ? 2u : (n1 ? 1u : 0u));
            ymin = min(ymin, y);      ymaxe = min(ymaxe, 511u - y);
            xmin = min(xmin, x + f);  xmaxe = min(xmaxe, 511u - (x + l));
        }
    }
#pragma unroll
    for (int off = 32; off; off >>= 1) {
        ymin  = min(ymin,  (unsigned)__shfl_xor((int)ymin,  off));
        ymaxe = min(ymaxe, (unsigned)__shfl_xor((int)ymaxe, off));
        xmin  = min(xmin,  (unsigned)__shfl_xor((int)xmin,  off));
        xmaxe = min(xmaxe, (unsigned)__shfl_xor((int)xmaxe, off));
    }
    __shared__ unsigned red[4][4];
    const int wv = threadIdx.x >> 6;
    if ((threadIdx.x & 63) == 0) {
        red[wv][0] = ymin; red[wv][1] = ymaxe; red[wv][2] = xmin; red[wv][3] = xmaxe;
    }
    __syncthreads();
    if (threadIdx.x < 4) {
        unsigned v = min(min(red[0][threadIdx.x], red[1][threadIdx.x]),
                         min(red[2][threadIdx.x], red[3][threadIdx.x]));
        if (v != ~0u)
            atomicMin(&slots[(blockIdx.x & (NSLOT - 1)) * 32 + b * 4 + (int)threadIdx.x], v);
    }
}

__global__ __launch_bounds__(256, 8)
void gdfn_all(const float* __restrict__ img,
              const float* __restrict__ noise,
              const float* __restrict__ re_mask,
              const int*   __restrict__ sel,
              const int*   __restrict__ mix_sel,
              float*       __restrict__ out,
              const unsigned* __restrict__ slots)
{
    constexpr int H = 512, W = 512, HP = 514, WP = 514;
    const int tid = threadIdx.x;

    // Fold bbox_reduce into every block: 64 slots x 32 words (L2-hot).
    __shared__ unsigned s_bbox[32];
    __shared__ int s_tile[8][4];   // ty0, tx0, tw, cnt
    __shared__ int s_rect[8][4];   // ry0, ry1, cx0, cx1 (tile-aligned pixel bounds)
    if (tid < 32) {
        unsigned m = ~0u;
#pragma unroll
        for (int s = 0; s < NSLOT; ++s) m = min(m, slots[s * 32 + tid]);
        s_bbox[tid] = m;
    }
    __syncthreads();
    if (tid < 8) {
        const int b = tid;
        int cnt = 0, ty0 = 0, tx0 = 0, tw = 1, ry0 = 0, ry1 = 0, cx0 = 0, cx1 = 0;
        if (sel[b]) {
            const unsigned e0 = s_bbox[b * 4 + 0];
            if (e0 <= 511u) {   // any mask!=1 seen (garbage can only over-cover)
                const unsigned e1 = min(s_bbox[b * 4 + 1], 511u);
                const unsigned e2 = min(s_bbox[b * 4 + 2], 511u);
                const unsigned e3 = min(s_bbox[b * 4 + 3], 511u);
                ty0 = (int)(e0 >> 3);
                const int ty1 = (int)((511u - e1) >> 3);
                tx0 = (int)(e2 >> 5);
                const int tx1 = (int)((511u - e3) >> 5);
                if (ty1 >= ty0 && tx1 >= tx0) {
                    tw  = tx1 - tx0 + 1;
                    cnt = (ty1 - ty0 + 1) * tw;
                    ry0 = ty0 << 3; ry1 = (ty1 + 1) << 3;
                    cx0 = tx0 << 5; cx1 = (tx1 + 1) << 5;
                }
            }
        }
        s_tile[b][0] = ty0; s_tile[b][1] = tx0; s_tile[b][2] = tw; s_tile[b][3] = cnt;
        s_rect[b][0] = ry0; s_rect[b][1] = ry1; s_rect[b][2] = cx0; s_rect[b][3] = cx1;
    }
    __syncthreads();

    const size_t HWs = (size_t)H * W;

    // ---------------- copy role ----------------
    if (blockIdx.x >= NHVY) {
        const int cb = (int)blockIdx.x - NHVY;
        const float4* img4 = (const float4*)img;
        float4*       out4 = (float4*)out;
        const int base = cb * 256 + tid;
#pragma unroll
        for (int it = 0; it < 3; ++it) {
            const int i = base + it * (NCPY * 256);
            const int b = i / 196608;
            const unsigned pix = ((unsigned)i & 65535u) << 2;
            const int y = (int)(pix >> 9), x = (int)(pix & 511u);
            const bool skip = (s_tile[b][3] > 0) &&
                              y >= s_rect[b][0] && y < s_rect[b][1] &&
                              x >= s_rect[b][2] && x < s_rect[b][3];
            if (!skip) out4[i] = img4[i];
        }
        return;
    }

    // ---------------- heavy role: grid-stride over enumerated 32x8 tiles ----------------
    int total = 0;
#pragma unroll
    for (int q = 0; q < 8; ++q) total += s_tile[q][3];

    __shared__ float s_imgp[3 * PH * PXS];  // 6552 B
    __shared__ float s_imgr[RH * RXS];      // 1776 B
    __shared__ float s_mod [MH * MXS];      // 1400 B

    for (int hid = blockIdx.x; hid < total; hid += NHVY) {
        __syncthreads();   // LDS reuse across grid-stride iterations

        int b = 0, rem = hid;
#pragma unroll
        for (int q = 0; q < 8; ++q) {
            const int c = s_tile[q][3];
            if (rem >= c && b == q) { rem -= c; b = q + 1; }
        }
        const int tw = s_tile[b][2];
        const int h0 = (s_tile[b][0] + rem / tw) * TSY;
        const int w0 = (s_tile[b][1] + rem % tw) * TSX;

        const size_t imgB = (size_t)b * 3 * HWs;
        const size_t noiB = (size_t)b * 3 * HP * WP;
        const int msel = mix_sel[b];

        // Stage-3 per-pixel loads issued early (overlap stages 0-2).
        const int t3y = tid >> 5, t3x = tid & 31;
        const int gy = h0 + t3y, gx = w0 + t3x;
        const size_t pb = imgB + (size_t)gy * W + gx;
        float img3v[3], rm3v[3];
#pragma unroll
        for (int c = 0; c < 3; ++c) {
            img3v[c] = img[pb + c * HWs];
            rm3v[c]  = re_mask[pb + c * HWs];
        }

        // Stage 0: img_p = pad(img,1)+noise over padded rows [h0-2,h0+11], cols [w0-2,w0+35].
#pragma unroll
        for (int it = 0; it < 7; ++it) {
            const int idx = tid + it * 256;
            if (idx < 3 * PH * PWX) {
                const int c  = idx / (PH * PWX);
                const int r  = idx - c * (PH * PWX);
                const int ly = r / PWX, lx = r - ly * PWX;
                const int py = h0 - 2 + ly, px = w0 - 2 + lx;
                float v = 0.f;
                if (py >= 0 && py < HP && px >= 0 && px < WP) {
                    v = noise[noiB + (size_t)c * HP * WP + (size_t)py * WP + px];
                    const int iy = py - 1, ix = px - 1;
                    if (iy >= 0 && iy < H && ix >= 0 && ix < W)
                        v += img[imgB + (size_t)c * HWs + (size_t)iy * W + ix];
                }
                s_imgp[c * PH * PXS + ly * PXS + lx] = v;
            }
        }
        __syncthreads();

        // Stage 1: img_r over 12x36 domain, all channels in registers.
        // w = exp(-(x-mean)^2/(2*std^2)), std^2(ddof=1)=ssd/8 => exp(-4 d^2/ssd)
#pragma unroll
        for (int it = 0; it < 2; ++it) {
            const int idx = tid + it * 256;
            if (idx < RH * RWX) {
                const int sy = idx / RWX, sx = idx - sy * RWX;
                const int ry = h0 - 2 + sy, rx = w0 - 2 + sx;
                if (ry >= 0 && ry < H && rx >= 0 && rx < W) {
                    float w3[9], vs[9];
#pragma unroll
                    for (int c = 0; c < 3; ++c) {
                        const float* sp = &s_imgp[c * PH * PXS + sy * PXS + sx];
                        float v[9];
                        float sum = 0.f;
#pragma unroll
                        for (int i = 0; i < 3; ++i)
#pragma unroll
                            for (int j = 0; j < 3; ++j) {
                                const float x = sp[i * PXS + j];
                                v[i * 3 + j] = x;
                                sum += x;
                            }
                        const float mean = sum * (1.f / 9.f);
                        float ssd = 0.f;
#pragma unroll
                        for (int k = 0; k < 9; ++k) { const float d = v[k] - mean; ssd += d * d; }
                        const float inv = -4.f / ssd;
#pragma unroll
                        for (int k = 0; k < 9; ++k) {
                            const float d  = v[k] - mean;
                            const float wv = __expf(d * d * inv);
                            if (c == 0) { w3[k] = wv;               vs[k] = v[k];  }
                            else        { w3[k] = fminf(w3[k], wv); vs[k] += v[k]; }
                        }
                    }
                    float num = 0.f, den = 0.f;
#pragma unroll
                    for (int k = 0; k < 9; ++k) {
                        den += w3[k];
                        num += vs[k] * w3[k];
                    }
                    s_imgr[sy * RXS + sx] = num / den;
                }
            }
        }
        __syncthreads();

        // Stage 2: 10x34 domain: first-occurrence argmin/argmax over img_r 3x3
        // (OOB = 0.0 exactly), then recompute selected weight (R4 formula).
#pragma unroll
        for (int it = 0; it < 2; ++it) {
            const int idx = tid + it * 256;
            if (idx < MH * MWX) {
                const int my = idx / MWX, mx = idx - my * MWX;
                const int qy = h0 - 1 + my, qx = w0 - 1 + mx;
                if (qy >= 0 && qy < H && qx >= 0 && qx < W) {
                    float bmin = 0.f, bmax = 0.f;
                    int imin = 0, imax = 0;
#pragma unroll
                    for (int k = 0; k < 9; ++k) {
                        const int di = k / 3 - 1, dj = k % 3 - 1;
                        const int ny = qy + di, nx = qx + dj;
                        float val = 0.f;
                        if (ny >= 0 && ny < H && nx >= 0 && nx < W)
                            val = s_imgr[(my + 1 + di) * RXS + (mx + 1 + dj)];
                        if (k == 0) { bmin = val; bmax = val; }
                        else {
                            if (val < bmin) { bmin = val; imin = k; }
                            if (val > bmax) { bmax = val; imax = k; }
                        }
                    }
                    const int ks = msel ? imax : imin;
                    const int si = ks / 3, sj = ks % 3;
                    float wmin = 1e30f;
#pragma unroll
                    for (int c = 0; c < 3; ++c) {
                        const float* sp = &s_imgp[c * PH * PXS + (my + 1) * PXS + (mx + 1)];
                        float vv[9];
                        float sum = 0.f;
#pragma unroll
                        for (int i = 0; i < 3; ++i)
#pragma unroll
                            for (int j = 0; j < 3; ++j) {
                                const float x = sp[i * PXS + j];
                                vv[i * 3 + j] = x;
                                sum += x;
                            }
                        const float mean = sum * (1.f / 9.f);
                        float ssd = 0.f;
#pragma unroll
                        for (int k = 0; k < 9; ++k) { const float d = vv[k] - mean; ssd += d * d; }
                        const float d  = vv[si * 3 + sj] - mean;
                        const float wv = __expf(d * d * (-4.f / ssd));
                        wmin = fminf(wmin, wv);
                    }
                    s_mod[my * MXS + mx] = wmin;
                }
            }
        }
        __syncthreads();

        // Stage 3: one channel per iteration, 256 px each; coalesced 128B row stores.
#pragma unroll
        for (int c3 = 0; c3 < 3; ++c3) {
            float m[9];
            float mden = 0.f;
#pragma unroll
            for (int k = 0; k < 9; ++k) {
                const int di = k / 3 - 1, dj = k % 3 - 1;
                const int ny = gy + di, nx = gx + dj;
                float mv = 0.f;
                if (ny >= 0 && ny < H && nx >= 0 && nx < W)
                    mv = s_mod[(t3y + di + 1) * MXS + (t3x + dj + 1)];
                m[k] = mv;
                mden += mv;
            }
            const float* sp = &s_imgp[c3 * PH * PXS + (t3y + 2) * PXS + (t3x + 2)];
            float numc = 0.f;
#pragma unroll
            for (int i = 0; i < 3; ++i)
#pragma unroll
                for (int j = 0; j < 3; ++j)
                    numc += sp[i * PXS + j] * m[i * 3 + j];
            const float imod = numc / mden;
            const float rm   = rm3v[c3];
            out[pb + c3 * HWs] = imod * (1.f - rm) + img3v[c3] * rm;
        }
    }
}

extern "C" void kernel_launch(void* const* d_in, const int* in_sizes, int n_in,
                              void* d_out, int out_size, void* d_ws, size_t ws_size,
                              hipStream_t stream)
{
    const float* img     = (const float*)d_in[0];
    const float* noise   = (const float*)d_in[1];
    const float* re_mask = (const float*)d_in[2];
    const int*   sel     = (const int*)d_in[3];
    const int*   mix_sel = (const int*)d_in[4];
    float*       out     = (float*)d_out;
    unsigned*    slots   = (unsigned*)d_ws;      // [64][32], poison 0xAA.. is min-safe

    hipLaunchKernelGGL(mask_scan, dim3(NMSK), dim3(256), 0, stream,
                       (const float4*)re_mask, sel, slots);
    hipLaunchKernelGGL(gdfn_all, dim3(NHVY + NCPY), dim3(256), 0, stream,
                       img, noise, re_mask, sel, mix_sel, out, slots);
}